// Round 3
// baseline (270.305 us; speedup 1.0000x reference)
//
#include <hip/hip_runtime.h>

// GCN: h1 = relu(Agg(x@W1) + b1); h2 = Agg(h1@W2) + b2; out = h2@Wc + bc
// Agg = symmetric-normalized adjacency with self-loops (PyG GCNConv).
// R13: issue-cost pass over the whole pipeline.
//  - hist/fill: 4 edges/thread via int4 loads -> 4x fewer blocks (was 25000).
//  - prep_bfrag (new, 3 tiny blocks): W1/W2/Wc MFMA B-fragments are identical
//    for every tile block -> precompute once into fb1/fb2/fb3; consumers load
//    8/4/2 half8 vector loads instead of 64/32/16 scalar dword loads.
//  - gathers: unified branchless masked 4-deep loop (masked lanes re-load the
//    batch head row -> L1 hit, ~free); __launch_bounds__(1024,8) caps VGPR at
//    64 -> 2 blocks/CU for the latency-bound gather.
//  - gemm1 pre-scales rows by dis[row] (R12); CSR build R5/R9 structure kept.

#define DIN 128
#define HID 128
#define FOUT 64

using half8 = __attribute__((ext_vector_type(8))) _Float16;
using float8 = __attribute__((ext_vector_type(8))) float;
using f32x4 = __attribute__((ext_vector_type(4))) float;

__device__ inline float8 cvt8(half8 v) {
  return __builtin_convertvector(v, float8);
}

// Deterministic dst->partition map (pure function; locality heuristic only).
__device__ inline int part_of(int d, float invn) {
  int p = (int)((float)d * invn);
  return p > 7 ? 7 : p;
}

// Partitioned histogram, 4 edges/thread: block b = chunk (b>>3) x part (b&7).
__global__ __launch_bounds__(256) void hist_kernel(
    const int* __restrict__ ei, int E, int* __restrict__ counts, float invn) {
  int part = blockIdx.x & 7;
  int e = (blockIdx.x >> 3) * 1024 + threadIdx.x * 4;
  if (e + 3 < E) {
    int4 d4 = *(const int4*)&ei[E + e];
    if (part_of(d4.x, invn) == part) atomicAdd(&counts[d4.x], 1);
    if (part_of(d4.y, invn) == part) atomicAdd(&counts[d4.y], 1);
    if (part_of(d4.z, invn) == part) atomicAdd(&counts[d4.z], 1);
    if (part_of(d4.w, invn) == part) atomicAdd(&counts[d4.w], 1);
  } else {
    for (int k = 0; k < 4; ++k) {
      if (e + k < E) {
        int d = ei[E + e + k];
        if (part_of(d, invn) == part) atomicAdd(&counts[d], 1);
      }
    }
  }
}

// One-kernel scan: block b computes base = sum counts[0..b*256) directly
// (coalesced strided read), local-scans its 256 chunk, fused node_init.
__global__ __launch_bounds__(256) void scan_fused_kernel(
    const int* __restrict__ counts, int N, int E, int* __restrict__ offsets,
    int* __restrict__ cursor, float* __restrict__ dis) {
  int t = threadIdx.x;
  int start = blockIdx.x * 256;

  int partial = 0;
  for (int i = t; i < start; i += 256) partial += counts[i];
#pragma unroll
  for (int off = 32; off > 0; off >>= 1)
    partial += __shfl_down(partial, off, 64);
  __shared__ int red[4];
  if ((t & 63) == 0) red[t >> 6] = partial;
  __syncthreads();
  int base = red[0] + red[1] + red[2] + red[3];

  int i = start + t;
  int c = (i < N) ? counts[i] : 0;
  __shared__ int s[256];
  s[t] = c;
  __syncthreads();
  for (int off = 1; off < 256; off <<= 1) {
    int u = 0;
    if (t >= off) u = s[t - off];
    __syncthreads();
    s[t] += u;
    __syncthreads();
  }
  int excl = s[t] - c + base;
  if (i < N) {
    offsets[i] = excl;
    cursor[i] = excl;
    dis[i] = rsqrtf((float)c + 1.0f);  // deg includes self-loop
  }
  if (i == N - 1) offsets[N] = E;
}

// Partitioned fill, 4 edges/thread.
__global__ __launch_bounds__(256) void fill_kernel(
    const int* __restrict__ ei, int E, int* __restrict__ cursor,
    int* __restrict__ csr, float invn) {
  int part = blockIdx.x & 7;
  int e = (blockIdx.x >> 3) * 1024 + threadIdx.x * 4;
  if (e + 3 < E) {
    int4 d4 = *(const int4*)&ei[E + e];
    int4 s4 = *(const int4*)&ei[e];
    if (part_of(d4.x, invn) == part) csr[atomicAdd(&cursor[d4.x], 1)] = s4.x;
    if (part_of(d4.y, invn) == part) csr[atomicAdd(&cursor[d4.y], 1)] = s4.y;
    if (part_of(d4.z, invn) == part) csr[atomicAdd(&cursor[d4.z], 1)] = s4.z;
    if (part_of(d4.w, invn) == part) csr[atomicAdd(&cursor[d4.w], 1)] = s4.w;
  } else {
    for (int k = 0; k < 4; ++k) {
      if (e + k < E) {
        int d = ei[E + e + k];
        if (part_of(d, invn) == part)
          csr[atomicAdd(&cursor[d], 1)] = ei[e + k];
      }
    }
  }
}

// Precompute MFMA B-fragments for W1/W2/Wc (identical for every tile block).
// fb1: [((s*2+ct)*256 + tid)*8], s<4, ct<2   (gemm1: K=128, NCOL=128) 32KB
// fb2: [(s*256 + tid)*8],        s<4         (gemm2: K=128, NCOL=64)  16KB
// fb3: [(s*256 + tid)*8],        s<2         (head:  K=64,  NCOL=64)   8KB
__global__ __launch_bounds__(256) void prep_bfrag_kernel(
    const float* __restrict__ W1, const float* __restrict__ W2,
    const float* __restrict__ Wc, _Float16* __restrict__ fb1,
    _Float16* __restrict__ fb2, _Float16* __restrict__ fb3) {
  int tid = threadIdx.x;
  int wave = tid >> 6, lane = tid & 63;
  int m = lane & 15, quad = lane >> 4;
  if (blockIdx.x == 0) {
#pragma unroll
    for (int ct = 0; ct < 2; ++ct) {
      int n = wave * 32 + ct * 16 + m;
#pragma unroll
      for (int s = 0; s < 4; ++s) {
        half8 h;
#pragma unroll
        for (int j = 0; j < 8; ++j)
          h[j] = (_Float16)W1[(size_t)(s * 32 + quad * 8 + j) * HID + n];
        *(half8*)&fb1[((s * 2 + ct) * 256 + tid) * 8] = h;
      }
    }
  } else if (blockIdx.x == 1) {
    int n = wave * 16 + m;
#pragma unroll
    for (int s = 0; s < 4; ++s) {
      half8 h;
#pragma unroll
      for (int j = 0; j < 8; ++j)
        h[j] = (_Float16)W2[(size_t)(s * 32 + quad * 8 + j) * FOUT + n];
      *(half8*)&fb2[(s * 256 + tid) * 8] = h;
    }
  } else {
    int n = wave * 16 + m;
#pragma unroll
    for (int s = 0; s < 2; ++s) {
      half8 h;
#pragma unroll
      for (int j = 0; j < 8; ++j)
        h[j] = (_Float16)Wc[(size_t)(s * 32 + quad * 8 + j) * FOUT + n];
      *(half8*)&fb3[(s * 256 + tid) * 8] = h;
    }
  }
}

// Tile MFMA GEMM (gemm1): C[M x NCOL] = A[M x K] @ W (fragments in FB),
// fp16 compute, fp32 accumulate; C fp16, pre-scaled by dis[row].
template <int K, int NCOL>
__global__ __launch_bounds__(256) void gemm_tile_kernel(
    const float* __restrict__ A, const _Float16* __restrict__ FB,
    const float* __restrict__ dis, _Float16* __restrict__ Cout, int M) {
  constexpr int KP = K + 8;     // halfs; (K+8)*2 B is a 16B multiple
  constexpr int KS = K / 32;    // k-steps
  constexpr int G8 = K / 8;     // half8 groups per row
  constexpr int NW = NCOL / 4;  // cols per wave
  constexpr int CT = NW / 16;   // 16-col tiles per wave
  __shared__ _Float16 As[64 * KP];

  int tid = threadIdx.x;
  int r0 = blockIdx.x * 64;

  // stage A tile (64 x K) fp32 -> fp16 LDS, coalesced global reads
  for (int g = tid; g < 64 * G8; g += 256) {
    int row = g / G8, c8 = g % G8;
    half8 h = (half8)(_Float16)0;
    if (r0 + row < M) {
      const float* ap = A + (size_t)(r0 + row) * K + c8 * 8;
      float4 a0 = *(const float4*)ap;
      float4 a1 = *(const float4*)(ap + 4);
      h[0] = (_Float16)a0.x; h[1] = (_Float16)a0.y;
      h[2] = (_Float16)a0.z; h[3] = (_Float16)a0.w;
      h[4] = (_Float16)a1.x; h[5] = (_Float16)a1.y;
      h[6] = (_Float16)a1.z; h[7] = (_Float16)a1.w;
    }
    *(half8*)&As[row * KP + c8 * 8] = h;
  }

  int wave = tid >> 6, lane = tid & 63;
  int m = lane & 15, quad = lane >> 4;
  int cw = wave * NW;

  // B fragments: precomputed, vector loads (wave reads 1KB contiguous).
  half8 b[CT][KS];
#pragma unroll
  for (int ct = 0; ct < CT; ++ct)
#pragma unroll
    for (int s = 0; s < KS; ++s)
      b[ct][s] = *(const half8*)&FB[((s * CT + ct) * 256 + tid) * 8];

  __syncthreads();

  f32x4 acc[4][CT];
#pragma unroll
  for (int rt = 0; rt < 4; ++rt)
#pragma unroll
    for (int ct = 0; ct < CT; ++ct) acc[rt][ct] = (f32x4){0.f, 0.f, 0.f, 0.f};

#pragma unroll
  for (int rt = 0; rt < 4; ++rt) {
#pragma unroll
    for (int s = 0; s < KS; ++s) {
      half8 af = *(half8*)&As[(rt * 16 + m) * KP + s * 32 + quad * 8];
#pragma unroll
      for (int ct = 0; ct < CT; ++ct)
        acc[rt][ct] = __builtin_amdgcn_mfma_f32_16x16x32_f16(
            af, b[ct][s], acc[rt][ct], 0, 0, 0);
    }
  }

  // epilogue: C col = cw+ct*16+m, row = r0+rt*16+quad*4+i, *dis[row]
#pragma unroll
  for (int rt = 0; rt < 4; ++rt) {
#pragma unroll
    for (int i = 0; i < 4; ++i) {
      int row = r0 + rt * 16 + quad * 4 + i;
      if (row >= M) continue;
      float d = dis[row];
#pragma unroll
      for (int ct = 0; ct < CT; ++ct)
        Cout[(size_t)row * NCOL + cw + ct * 16 + m] =
            (_Float16)(acc[rt][ct][i] * d);
    }
  }
}

// Fused layer-1 gather + gemm2. Block = 16 waves = 16 nodes.
// hw rows PRE-SCALED by dis[row]; gather = pure row-sum.
// h1 = relu(dn*(sum hws[s] + hws[n]) + b1) -> fp16 LDS row; waves 0..3 then
// compute the 16x64 K=128 tile (h1 @ W2)*dis -> hw2 fp16.
__global__ __launch_bounds__(1024, 8) void gather1_gemm2_kernel(
    const _Float16* __restrict__ hw, const float* __restrict__ dis,
    const int* __restrict__ off, const int* __restrict__ csr,
    const float* __restrict__ b1, const _Float16* __restrict__ fb2,
    _Float16* __restrict__ hw2, int N) {
  constexpr int F = HID;        // 128
  constexpr int FC = F / 8;     // 16 lanes per row-chunk
  constexpr int EPW = 64 / FC;  // 4 edge slots
  constexpr int KP = F + 8;
  __shared__ _Float16 As[16 * KP];

  int wave = threadIdx.x >> 6;
  int lane = threadIdx.x & 63;
  int eslot = lane / FC;
  int c = lane % FC;
  int n = blockIdx.x * 16 + wave;

  if (n < N) {
    const half8* hw8 = (const half8*)hw;
    float8 acc0 = {0.f, 0.f, 0.f, 0.f, 0.f, 0.f, 0.f, 0.f};
    float8 acc1 = {0.f, 0.f, 0.f, 0.f, 0.f, 0.f, 0.f, 0.f};
    if (eslot == 0)  // self loop: hws[n] (outer *dn gives dn^2*hw[n])
      acc0 = cvt8(hw8[(size_t)n * FC + c]);

    int j0 = off[n], j1 = off[n + 1];
    // unified branchless masked 4-deep loop; masked lanes re-load the batch
    // head row (same address -> L1 hit).
    for (int j = j0 + eslot; j < j1; j += 4 * EPW) {
      int i1 = j + EPW, i2 = j + 2 * EPW, i3 = j + 3 * EPW;
      int s0 = csr[j];
      int s1 = csr[i1 < j1 ? i1 : j];
      int s2 = csr[i2 < j1 ? i2 : j];
      int s3 = csr[i3 < j1 ? i3 : j];
      float m1 = i1 < j1 ? 1.f : 0.f;
      float m2 = i2 < j1 ? 1.f : 0.f;
      float m3 = i3 < j1 ? 1.f : 0.f;
      half8 v0 = hw8[(size_t)s0 * FC + c];
      half8 v1 = hw8[(size_t)s1 * FC + c];
      half8 v2 = hw8[(size_t)s2 * FC + c];
      half8 v3 = hw8[(size_t)s3 * FC + c];
      acc0 += cvt8(v0);
      acc1 += cvt8(v1) * m1;
      acc0 += cvt8(v2) * m2;
      acc1 += cvt8(v3) * m3;
    }
    acc0 += acc1;

#pragma unroll
    for (int st = FC; st < 64; st <<= 1) {
#pragma unroll
      for (int i = 0; i < 8; ++i) acc0[i] += __shfl_xor(acc0[i], st, 64);
    }

    if (eslot == 0) {
      float dn = dis[n];
      half8 h;
#pragma unroll
      for (int i = 0; i < 8; ++i)
        h[i] = (_Float16)fmaxf(fmaf(acc0[i], dn, b1[c * 8 + i]), 0.f);
      *(half8*)&As[wave * KP + c * 8] = h;
    }
  } else {
    if (eslot == 0) *(half8*)&As[wave * KP + c * 8] = (half8)(_Float16)0;
  }

  // W2 fragments: precomputed (fb2), 4 vector loads.
  int m = lane & 15, quad = lane >> 4;
  half8 b[4];
  f32x4 a4 = {0.f, 0.f, 0.f, 0.f};
  int tid = threadIdx.x;
  if (wave < 4) {
#pragma unroll
    for (int s = 0; s < 4; ++s)
      b[s] = *(const half8*)&fb2[(s * 256 + tid) * 8];
  }
  __syncthreads();

  if (wave < 4) {
#pragma unroll
    for (int s = 0; s < 4; ++s) {
      half8 af = *(half8*)&As[m * KP + s * 32 + quad * 8];
      a4 = __builtin_amdgcn_mfma_f32_16x16x32_f16(af, b[s], a4, 0, 0, 0);
    }
    int nc = wave * 16 + m;
#pragma unroll
    for (int i = 0; i < 4; ++i) {
      int row = blockIdx.x * 16 + quad * 4 + i;
      if (row < N)
        hw2[(size_t)row * FOUT + nc] = (_Float16)(a4[i] * dis[row]);
    }
  }
}

// Fused layer-2 gather + head gemm. Block = 16 waves = 16 nodes.
// Gather PRE-SCALED fp16 hw2 rows; h2 = dn*acc + b2 -> fp32 out_h2 (output 0)
// AND fp16 LDS row; waves 0..3 compute out_y = h2 @ Wc + bc (16x64, K=64).
__global__ __launch_bounds__(1024, 8) void gather2_head_kernel(
    const _Float16* __restrict__ hw, const float* __restrict__ dis,
    const int* __restrict__ off, const int* __restrict__ csr,
    const float* __restrict__ b2, const _Float16* __restrict__ fb3,
    const float* __restrict__ bc, float* __restrict__ out_h2,
    float* __restrict__ out_y, int N) {
  constexpr int F = FOUT;       // 64
  constexpr int FC = F / 8;     // 8 lanes per row-chunk
  constexpr int EPW = 64 / FC;  // 8 edge slots
  constexpr int KP = F + 8;
  __shared__ _Float16 As[16 * KP];

  int wave = threadIdx.x >> 6;
  int lane = threadIdx.x & 63;
  int eslot = lane / FC;
  int c = lane % FC;
  int n = blockIdx.x * 16 + wave;

  if (n < N) {
    const half8* hw8 = (const half8*)hw;
    float8 acc0 = {0.f, 0.f, 0.f, 0.f, 0.f, 0.f, 0.f, 0.f};
    float8 acc1 = {0.f, 0.f, 0.f, 0.f, 0.f, 0.f, 0.f, 0.f};
    if (eslot == 0)  // self loop (row pre-scaled by dis[n])
      acc0 = cvt8(hw8[(size_t)n * FC + c]);

    int j0 = off[n], j1 = off[n + 1];
    for (int j = j0 + eslot; j < j1; j += 4 * EPW) {
      int i1 = j + EPW, i2 = j + 2 * EPW, i3 = j + 3 * EPW;
      int s0 = csr[j];
      int s1 = csr[i1 < j1 ? i1 : j];
      int s2 = csr[i2 < j1 ? i2 : j];
      int s3 = csr[i3 < j1 ? i3 : j];
      float m1 = i1 < j1 ? 1.f : 0.f;
      float m2 = i2 < j1 ? 1.f : 0.f;
      float m3 = i3 < j1 ? 1.f : 0.f;
      half8 v0 = hw8[(size_t)s0 * FC + c];
      half8 v1 = hw8[(size_t)s1 * FC + c];
      half8 v2 = hw8[(size_t)s2 * FC + c];
      half8 v3 = hw8[(size_t)s3 * FC + c];
      acc0 += cvt8(v0);
      acc1 += cvt8(v1) * m1;
      acc0 += cvt8(v2) * m2;
      acc1 += cvt8(v3) * m3;
    }
    acc0 += acc1;

#pragma unroll
    for (int st = FC; st < 64; st <<= 1) {
#pragma unroll
      for (int i = 0; i < 8; ++i) acc0[i] += __shfl_xor(acc0[i], st, 64);
    }

    if (eslot == 0) {
      float dn = dis[n];
      float4 bb0 = *(const float4*)&b2[c * 8 + 0];
      float4 bb1 = *(const float4*)&b2[c * 8 + 4];
      float4 r0 =
          make_float4(fmaf(acc0[0], dn, bb0.x), fmaf(acc0[1], dn, bb0.y),
                      fmaf(acc0[2], dn, bb0.z), fmaf(acc0[3], dn, bb0.w));
      float4 r1 =
          make_float4(fmaf(acc0[4], dn, bb1.x), fmaf(acc0[5], dn, bb1.y),
                      fmaf(acc0[6], dn, bb1.z), fmaf(acc0[7], dn, bb1.w));
      float* op = out_h2 + (size_t)n * F + c * 8;
      *(float4*)(op + 0) = r0;
      *(float4*)(op + 4) = r1;
      half8 h;
      h[0] = (_Float16)r0.x; h[1] = (_Float16)r0.y;
      h[2] = (_Float16)r0.z; h[3] = (_Float16)r0.w;
      h[4] = (_Float16)r1.x; h[5] = (_Float16)r1.y;
      h[6] = (_Float16)r1.z; h[7] = (_Float16)r1.w;
      *(half8*)&As[wave * KP + c * 8] = h;
    }
  } else {
    if (eslot == 0) *(half8*)&As[wave * KP + c * 8] = (half8)(_Float16)0;
  }

  // Wc fragments: precomputed (fb3), 2 vector loads.
  int m = lane & 15, quad = lane >> 4;
  half8 b[2];
  float bval = 0.f;
  f32x4 a4 = {0.f, 0.f, 0.f, 0.f};
  int tid = threadIdx.x;
  if (wave < 4) {
#pragma unroll
    for (int s = 0; s < 2; ++s)
      b[s] = *(const half8*)&fb3[(s * 256 + tid) * 8];
    bval = bc[wave * 16 + m];
  }
  __syncthreads();

  if (wave < 4) {
#pragma unroll
    for (int s = 0; s < 2; ++s) {
      half8 af = *(half8*)&As[m * KP + s * 32 + quad * 8];
      a4 = __builtin_amdgcn_mfma_f32_16x16x32_f16(af, b[s], a4, 0, 0, 0);
    }
    int nc = wave * 16 + m;
#pragma unroll
    for (int i = 0; i < 4; ++i) {
      int row = blockIdx.x * 16 + quad * 4 + i;
      if (row < N) out_y[(size_t)row * FOUT + nc] = a4[i] + bval;
    }
  }
}

extern "C" void kernel_launch(void* const* d_in, const int* in_sizes, int n_in,
                              void* d_out, int out_size, void* d_ws,
                              size_t ws_size, hipStream_t stream) {
  const float* x = (const float*)d_in[0];
  const int* ei = (const int*)d_in[1];
  const float* W1 = (const float*)d_in[2];
  const float* b1 = (const float*)d_in[3];
  const float* W2 = (const float*)d_in[4];
  const float* b2 = (const float*)d_in[5];
  const float* Wc = (const float*)d_in[6];
  const float* bc = (const float*)d_in[7];

  int N = in_sizes[0] / DIN;
  int E = in_sizes[1] / 2;
  int nper = (N + 7) / 8;           // dst-range partition size
  float invn = 1.0f / (float)nper;  // deterministic partition map scale

  char* w = (char*)d_ws;
  size_t off = 0;
  auto alloc = [&](size_t bytes) {
    char* p = w + off;
    off += (bytes + 255) & ~(size_t)255;
    return p;
  };
  int* counts = (int*)alloc((size_t)N * 4);
  int* offsets = (int*)alloc((size_t)(N + 1) * 4);
  int* cursor = (int*)alloc((size_t)N * 4);
  int* csr = (int*)alloc((size_t)E * 4);
  float* dis = (float*)alloc((size_t)N * 4);
  _Float16* hw1 = (_Float16*)alloc((size_t)N * DIN * 2);   // fp16, PRE-scaled
  _Float16* hw2 = (_Float16*)alloc((size_t)N * FOUT * 2);  // fp16, PRE-scaled
  _Float16* fb1 = (_Float16*)alloc(8 * 256 * 8 * 2);       // gemm1 B frags
  _Float16* fb2 = (_Float16*)alloc(4 * 256 * 8 * 2);       // gemm2 B frags
  _Float16* fb3 = (_Float16*)alloc(2 * 256 * 8 * 2);       // head  B frags

  float* out_h2 = (float*)d_out;             // output 0: h2 [N x 64]
  float* out_y = out_h2 + (size_t)N * FOUT;  // output 1: out [N x 64]

  hipMemsetAsync(counts, 0, (size_t)N * 4, stream);

  int evgrid = (E + 1023) / 1024;  // 4 edges/thread
  int ngrid = (N + 255) / 256;
  int tgrid = (N + 63) / 64;  // gemm1: one 64-row tile per block
  int fgrid = (N + 15) / 16;  // fused gather+gemm: 16 nodes per block

  prep_bfrag_kernel<<<3, 256, 0, stream>>>(W1, W2, Wc, fb1, fb2, fb3);
  hist_kernel<<<evgrid * 8, 256, 0, stream>>>(ei, E, counts, invn);
  scan_fused_kernel<<<ngrid, 256, 0, stream>>>(counts, N, E, offsets, cursor,
                                               dis);
  fill_kernel<<<evgrid * 8, 256, 0, stream>>>(ei, E, cursor, csr, invn);

  // layer 1 transform: hw1 = (x @ W1)*dis (fp16, pre-scaled)
  gemm_tile_kernel<DIN, HID><<<tgrid, 256, 0, stream>>>(x, fb1, dis, hw1, N);

  // fused: h1 = relu(dn*Agg(hws1) + b1); hw2 = (h1 @ W2)*dis (fp16)
  gather1_gemm2_kernel<<<fgrid, 1024, 0, stream>>>(hw1, dis, offsets, csr, b1,
                                                   fb2, hw2, N);

  // fused: h2 = dn*Agg(hws2) + b2 -> out_h2 (fp32); out_y = h2 @ Wc + bc
  gather2_head_kernel<<<fgrid, 1024, 0, stream>>>(hw2, dis, offsets, csr, b2,
                                                  fb3, bc, out_h2, out_y, N);
}